// Round 12
// baseline (560.892 us; speedup 1.0000x reference)
//
#include <hip/hip_runtime.h>
#include <hip/hip_bf16.h>

// Problem constants
#define R_TOT   8192
#define A14     14
#define A_TOT   (R_TOT * A14)     // 114688
#define QR_ELEMS (R_TOT * 256)    // 2097152

typedef __attribute__((ext_vector_type(8))) short bf16x8;
typedef __attribute__((ext_vector_type(4))) float f32x4;
typedef __attribute__((ext_vector_type(4))) short short4v;

#define MFMA16(a, b, c) __builtin_amdgcn_mfma_f32_16x16x32_bf16((a), (b), (c), 0, 0, 0)

static __device__ __forceinline__ float b2f(short s) {
    return __uint_as_float(((unsigned)(unsigned short)s) << 16);
}

// ---------------------------------------------------------------------------
// Merged weight transpose + bf16 cast: all 7 weights in one launch.
// ---------------------------------------------------------------------------
static __device__ __forceinline__ void wtrans_tile(
    const float* __restrict__ w, __hip_bfloat16* __restrict__ wT,
    int K, int N, int kb, int nb, float* tile /*[32][33]*/)
{
    const int tx = threadIdx.x & 31, ty = threadIdx.x >> 5;   // 32 x 8
    #pragma unroll
    for (int i = 0; i < 32; i += 8) {
        int k = kb + ty + i, n = nb + tx;
        tile[(ty + i) * 33 + tx] = (k < K && n < N) ? w[(size_t)k * N + n] : 0.f;
    }
    __syncthreads();
    #pragma unroll
    for (int i = 0; i < 32; i += 8) {
        int n = nb + ty + i, k = kb + tx;
        if (n < N && k < K) wT[(size_t)n * K + k] = __float2bfloat16(tile[tx * 33 + ty + i]);
    }
}

__global__ __launch_bounds__(256) void wtrans_all_kernel(
    const float* __restrict__ sw1, __hip_bfloat16* __restrict__ wT1,
    const float* __restrict__ sw2, __hip_bfloat16* __restrict__ wT2,
    const float* __restrict__ sw3, __hip_bfloat16* __restrict__ wT3,
    const float* __restrict__ zw1, __hip_bfloat16* __restrict__ zT1,
    const float* __restrict__ zw2, __hip_bfloat16* __restrict__ zT2,
    const float* __restrict__ zw3, __hip_bfloat16* __restrict__ zT3,
    const float* __restrict__ zvw, __hip_bfloat16* __restrict__ vT)
{
    __shared__ float tile[32 * 33];
    int b = blockIdx.x;
    if (b < 128)      { wtrans_tile(sw1, wT1, 512, 256, (b % 16) * 32, (b / 16) * 32, tile); return; }
    b -= 128;
    if (b < 64)       { wtrans_tile(sw2, wT2, 256, 256, (b % 8) * 32, (b / 8) * 32, tile); return; }
    b -= 64;
    if (b < 8)        { wtrans_tile(sw3, wT3, 256, 16,  b * 32, 0, tile); return; }
    b -= 8;
    if (b < 512)      { wtrans_tile(zw1, zT1, 2048, 256, (b % 64) * 32, (b / 64) * 32, tile); return; }
    b -= 512;
    if (b < 64)       { wtrans_tile(zw2, zT2, 256, 256, (b % 8) * 32, (b / 8) * 32, tile); return; }
    b -= 64;
    if (b < 64)       { wtrans_tile(zw3, zT3, 256, 256, (b % 8) * 32, (b / 8) * 32, tile); return; }
    b -= 64;
    wtrans_tile(zvw, vT, 2048, 256, (b % 64) * 32, (b / 64) * 32, tile);
}

// ---------------------------------------------------------------------------
// Fused sam MLP + masked softmax + pooling, v9: register-lean for occupancy.
// Occupancy model (fitted rounds 2-11): waves/SIMD = floor(512 /
// round16(VGPR+AGPR)).  acc[4][4] = 64 AGPR; target arch-VGPR <= 96 so total
// 160 -> 3 waves/SIMD = 12 waves/CU (was 2/SIMD at 168+).
// Changes vs v8: no T14 register staging (sync norm stage), B-prefetch
// depth 1 (was 2), launch_bounds(256,3) pins the allocator budget.
// Single time-multiplexed [64][264] buffer (q-half -> norm-half -> h1 -> h2).
// LDS: 39,680 B (not the binder at 12 waves: 3 blocks/CU).
// ---------------------------------------------------------------------------
__global__ __launch_bounds__(256, 3) void sampool_kernel(
    const float* __restrict__ q, const float* __restrict__ p,
    const float* __restrict__ atom_mask,
    const __hip_bfloat16* __restrict__ wT1, const float* __restrict__ b1,
    const __hip_bfloat16* __restrict__ wT2, const float* __restrict__ b2,
    const __hip_bfloat16* __restrict__ wT3, const float* __restrict__ b3,
    __hip_bfloat16* __restrict__ qh, __hip_bfloat16* __restrict__ ph)
{
    __shared__ __align__(16) __hip_bfloat16 zl[64][264];          // 33,792 B
    __shared__ float sa_lds[64][16];                              //  4,096 B
    __shared__ __align__(16) __hip_bfloat16 aw_lds[2][4][14][8];  //  1,792 B

    const int tid = threadIdx.x;
    const int r0  = blockIdx.x * 4;      // 4 residues
    const int a0  = r0 * A14;            // 56 real atom rows, pad to 64
    const int wv  = tid >> 6;            // 0..3
    const int l   = tid & 63;
    const int lr  = l & 15;
    const int lh  = l >> 4;
    const int nbase = wv * 64;

    // ---- stage q-half into zbuf: 64 rows x 256 cols ----
    #pragma unroll 4
    for (int it = 0; it < 16; ++it) {
        const int g  = tid + it * 256;       // 0..4095
        const int m  = g >> 6;               // 0..63
        const int c4 = (g & 63) * 4;         // 0..252
        const int ar = a0 + m;
        const size_t arow = (size_t)((ar < A_TOT) ? ar : (A_TOT - 1));
        const float4 v = *(const float4*)&q[arow * 256 + c4];
        __hip_bfloat16 t[4];
        t[0] = __float2bfloat16(v.x); t[1] = __float2bfloat16(v.y);
        t[2] = __float2bfloat16(v.z); t[3] = __float2bfloat16(v.w);
        *(short4v*)&zl[m][c4] = *(const short4v*)t;
    }
    __syncthreads();   // (A) q-half staged

    // ---- Layer 1 in two K-halves over the SAME buffer; acc persists ----
    f32x4 acc[4][4] = {};
    const __hip_bfloat16* pB[4];
    #pragma unroll
    for (int nt = 0; nt < 4; ++nt)
        pB[nt] = wT1 + (size_t)(nbase + nt * 16 + lr) * 512 + lh * 8;

    // A reads always from zbuf cols 0-255; weight offset KB selects the half.
    // B-prefetch depth 1, A-prefetch depth 1.
    #define L1_HALF(KB)                                                        \
        {                                                                      \
            bf16x8 bc[4];                                                      \
            _Pragma("unroll")                                                  \
            for (int nt = 0; nt < 4; ++nt)                                     \
                bc[nt] = *(const bf16x8*)(pB[nt] + (KB));                      \
            bf16x8 ac[4];                                                      \
            _Pragma("unroll")                                                  \
            for (int mf = 0; mf < 4; ++mf)                                     \
                ac[mf] = *(const bf16x8*)&zl[mf * 16 + lr][lh * 8];            \
            _Pragma("unroll")                                                  \
            for (int k0 = 0; k0 < 256; k0 += 32) {                             \
                bf16x8 bn[4], an[4];                                           \
                if (k0 + 32 < 256) {                                           \
                    _Pragma("unroll")                                          \
                    for (int nt = 0; nt < 4; ++nt)                             \
                        bn[nt] = *(const bf16x8*)(pB[nt] + (KB) + k0 + 32);    \
                    _Pragma("unroll")                                          \
                    for (int mf = 0; mf < 4; ++mf)                             \
                        an[mf] = *(const bf16x8*)&zl[mf * 16 + lr][k0 + 32 + lh * 8]; \
                }                                                              \
                _Pragma("unroll")                                              \
                for (int mf = 0; mf < 4; ++mf)                                 \
                    _Pragma("unroll")                                          \
                    for (int nt = 0; nt < 4; ++nt)                             \
                        acc[mf][nt] = MFMA16(ac[mf], bc[nt], acc[mf][nt]);     \
                _Pragma("unroll")                                              \
                for (int nt = 0; nt < 4; ++nt) bc[nt] = bn[nt];                \
                _Pragma("unroll")                                              \
                for (int mf = 0; mf < 4; ++mf) ac[mf] = an[mf];                \
            }                                                                  \
        }

    // part 1: k = 0..255 (q-half)
    L1_HALF(0);
    __syncthreads();   // (B) all waves done reading q-half

    // ---- overwrite buffer with norm-half (synchronous, lean) ----
    #pragma unroll 4
    for (int it = 0; it < 16; ++it) {
        const int g  = tid + it * 256;
        const int m  = g >> 6;
        const int cc = (g & 63) * 4;
        const int ar = a0 + m;
        const size_t arow = (size_t)((ar < A_TOT) ? ar : (A_TOT - 1));
        const float* base = p + arow * 768 + cc;
        const float4 pa = *(const float4*)(base);
        const float4 pb = *(const float4*)(base + 256);
        const float4 pc = *(const float4*)(base + 512);
        __hip_bfloat16 t[4];
        t[0] = __float2bfloat16(sqrtf(pa.x*pa.x + pb.x*pb.x + pc.x*pc.x + 1e-6f));
        t[1] = __float2bfloat16(sqrtf(pa.y*pa.y + pb.y*pb.y + pc.y*pc.y + 1e-6f));
        t[2] = __float2bfloat16(sqrtf(pa.z*pa.z + pb.z*pb.z + pc.z*pc.z + 1e-6f));
        t[3] = __float2bfloat16(sqrtf(pa.w*pa.w + pb.w*pb.w + pc.w*pc.w + 1e-6f));
        *(short4v*)&zl[m][cc] = *(const short4v*)t;
    }
    __syncthreads();   // (C) norm-half staged

    // part 2: k = 256..511 (norm half)
    L1_HALF(256);
    __syncthreads();   // (D) all waves done reading norm half

    // bias + leaky -> h1 (same buffer, in place)
    #pragma unroll
    for (int nt = 0; nt < 4; ++nt) {
        const int n = nbase + nt * 16 + lr;
        const float bv = b1[n];
        #pragma unroll
        for (int mf = 0; mf < 4; ++mf)
            #pragma unroll
            for (int v = 0; v < 4; ++v) {
                float x = acc[mf][nt][v] + bv;
                x = x >= 0.f ? x : 0.01f * x;
                zl[mf * 16 + lh * 4 + v][n] = __float2bfloat16(x);  // h1
            }
    }
    __syncthreads();   // (E) h1 complete

    // ---- Layer 2: K=256, leaky; A=h1, h2 in place ----
    {
        f32x4 acc2[4][4] = {};
        const __hip_bfloat16* pB2[4];
        #pragma unroll
        for (int nt = 0; nt < 4; ++nt)
            pB2[nt] = wT2 + (size_t)(nbase + nt * 16 + lr) * 256 + lh * 8;
        bf16x8 bc[4];
        #pragma unroll
        for (int nt = 0; nt < 4; ++nt) bc[nt] = *(const bf16x8*)(pB2[nt]);
        bf16x8 ac[4];
        #pragma unroll
        for (int mf = 0; mf < 4; ++mf)
            ac[mf] = *(const bf16x8*)&zl[mf * 16 + lr][lh * 8];

        #pragma unroll
        for (int k0 = 0; k0 < 256; k0 += 32) {
            bf16x8 bn[4], an[4];
            if (k0 + 32 < 256) {
                #pragma unroll
                for (int nt = 0; nt < 4; ++nt)
                    bn[nt] = *(const bf16x8*)(pB2[nt] + k0 + 32);
                #pragma unroll
                for (int mf = 0; mf < 4; ++mf)
                    an[mf] = *(const bf16x8*)&zl[mf * 16 + lr][k0 + 32 + lh * 8];
            }
            #pragma unroll
            for (int mf = 0; mf < 4; ++mf)
                #pragma unroll
                for (int nt = 0; nt < 4; ++nt)
                    acc2[mf][nt] = MFMA16(ac[mf], bc[nt], acc2[mf][nt]);
            #pragma unroll
            for (int nt = 0; nt < 4; ++nt) bc[nt] = bn[nt];
            #pragma unroll
            for (int mf = 0; mf < 4; ++mf) ac[mf] = an[mf];
        }
        __syncthreads();   // (F) all reads of h1 done
        #pragma unroll
        for (int nt = 0; nt < 4; ++nt) {
            const int n = nbase + nt * 16 + lr;
            const float bv = b2[n];
            #pragma unroll
            for (int mf = 0; mf < 4; ++mf)
                #pragma unroll
                for (int v = 0; v < 4; ++v) {
                    float x = acc2[mf][nt][v] + bv;
                    x = x >= 0.f ? x : 0.01f * x;
                    zl[mf * 16 + lh * 4 + v][n] = __float2bfloat16(x);  // h2
                }
        }
    }
    __syncthreads();   // (G) h2 complete

    // ---- Layer 3: K=256 -> 16 cols; wave wv owns m-frag wv ----
    {
        f32x4 a3 = {};
        const __hip_bfloat16* pW3 = wT3 + (size_t)lr * 256 + lh * 8;
        bf16x8 bwc = *(const bf16x8*)(pW3);
        #pragma unroll
        for (int k0 = 0; k0 < 256; k0 += 32) {
            bf16x8 bwn;
            if (k0 + 32 < 256) bwn = *(const bf16x8*)(pW3 + k0 + 32);
            const bf16x8 af = *(const bf16x8*)&zl[wv * 16 + lr][k0 + lh * 8];
            a3 = MFMA16(af, bwc, a3);
            bwc = bwn;
        }
        const float bv = b3[lr];
        #pragma unroll
        for (int v = 0; v < 4; ++v)
            sa_lds[wv * 16 + lh * 4 + v][lr] = a3[v] + bv;
    }
    __syncthreads();   // (H) sa complete

    // ---- masked softmax: 4 residues x 16 channels = 64 threads (wave 0) ----
    if (tid < 64) {
        const int res = tid >> 4, ch = tid & 15;
        const size_t rg = (size_t)(r0 + res);
        float sl[14];
        float mx = -3.0e38f, anym = 0.f;
        #pragma unroll
        for (int a = 0; a < 14; ++a) {
            const float m = atom_mask[rg * 14 + a];
            anym = fmaxf(anym, m);
            const float lm = (1.0f - m + 1e-6f) / (m - 1e-6f);
            const float v = sa_lds[res * 14 + a][ch] + lm;
            sl[a] = v;
            mx = fmaxf(mx, v);
        }
        float s = 0.f;
        #pragma unroll
        for (int a = 0; a < 14; ++a) { sl[a] = expf(sl[a] - mx); s += sl[a]; }
        const float inv = ((anym != 0.f) ? 1.f : 0.f) / s;   // fold residue mask
        const int h = ch >> 1;
        #pragma unroll
        for (int a = 0; a < 14; ++a)
            aw_lds[ch & 1][res][a][h] = __float2bfloat16(sl[a] * inv);
    }
    __syncthreads();   // (I) aw complete

    // ---- pooling: 1024 jobs = 4 res x {q,px0,px1,px2} x 64 c-quads ----
    #pragma unroll
    for (int jr = 0; jr < 4; ++jr) {
        const int job = tid + jr * 256;
        const int res = job >> 8;            // 0..3
        const int s   = (job >> 6) & 3;      // 0:q  1..3:p[x]
        const int c4  = (job & 63) * 4;
        const size_t rg = (size_t)(r0 + res);
        const __hip_bfloat16* const awp = &aw_lds[(s == 0) ? 0 : 1][res][0][0];
        const float* src;
        size_t stride;
        if (s == 0) { src = &q[(rg * 14) * 256 + c4]; stride = 256; }
        else        { src = &p[(rg * 14) * 768 + (size_t)(s - 1) * 256 + c4]; stride = 768; }
        float acc4[4][8] = {};
        #pragma unroll
        for (int a = 0; a < 14; ++a) {
            const float4 v = *(const float4*)(src + (size_t)a * stride);
            const float vf[4] = { v.x, v.y, v.z, v.w };
            const short4v w0 = *(const short4v*)&awp[a * 8];
            const short4v w1 = *(const short4v*)&awp[a * 8 + 4];
            const float wf[8] = { b2f(w0.x), b2f(w0.y), b2f(w0.z), b2f(w0.w),
                                  b2f(w1.x), b2f(w1.y), b2f(w1.z), b2f(w1.w) };
            #pragma unroll
            for (int ci = 0; ci < 4; ++ci)
                #pragma unroll
                for (int h = 0; h < 8; ++h)
                    acc4[ci][h] = fmaf(vf[ci], wf[h], acc4[ci][h]);
        }
        alignas(16) __hip_bfloat16 tmp[32];
        #pragma unroll
        for (int ci = 0; ci < 4; ++ci)
            #pragma unroll
            for (int h = 0; h < 8; ++h)
                tmp[ci * 8 + h] = __float2bfloat16(acc4[ci][h]);
        __hip_bfloat16* const dst = (s == 0)
            ? &qh[rg * 2048 + (size_t)c4 * 8]
            : &ph[(rg * 3 + (s - 1)) * 2048 + (size_t)c4 * 8];
        #pragma unroll
        for (int u = 0; u < 4; ++u)
            *reinterpret_cast<int4*>(dst + u * 8) = *reinterpret_cast<const int4*>(tmp + u * 8);
    }
    #undef L1_HALF
}

// ---------------------------------------------------------------------------
// Merged tail: blocks 0..255 run zdm (qh -> qr), blocks 256..1023 run pr
// (ph @ vT -> pr).
// ---------------------------------------------------------------------------
__global__ __launch_bounds__(256, 3) void tail_kernel(
    const __hip_bfloat16* __restrict__ qh, const __hip_bfloat16* __restrict__ ph,
    const __hip_bfloat16* __restrict__ zT1, const float* __restrict__ zb1,
    const __hip_bfloat16* __restrict__ zT2, const float* __restrict__ zb2,
    const __hip_bfloat16* __restrict__ zT3, const float* __restrict__ zb3,
    const __hip_bfloat16* __restrict__ vT,
    float* __restrict__ qr, float* __restrict__ pr)
{
    __shared__ __align__(16) __hip_bfloat16 xl[2][32][264];  // 33,792 B
    __shared__ __align__(16) __hip_bfloat16 hl[32][264];     // 16,896 B

    const int tid = threadIdx.x;
    const int wv  = tid >> 6;
    const int l   = tid & 63;
    const int lr  = l & 15;
    const int lh  = l >> 4;
    const int nbase = wv * 64;
    const bool is_zdm = (blockIdx.x < 256);
    const int a0 = (is_zdm ? blockIdx.x : (blockIdx.x - 256)) * 32;
    const __hip_bfloat16* const x = is_zdm ? qh : ph;
    const __hip_bfloat16* const w1 = is_zdm ? zT1 : vT;

    int4 st[4];
    #define LOADC(c)                                                          \
        { _Pragma("unroll")                                                   \
          for (int it = 0; it < 4; ++it) {                                    \
              const int g = tid + it * 256;                                   \
              const int m = g >> 5, c8 = (g & 31) * 8;                        \
              st[it] = *(const int4*)&x[(size_t)(a0 + m) * 2048 + (c) * 256 + c8]; } }
    #define WRITEC(buf)                                                       \
        { _Pragma("unroll")                                                   \
          for (int it = 0; it < 4; ++it) {                                    \
              const int g = tid + it * 256;                                   \
              const int m = g >> 5, c8 = (g & 31) * 8;                        \
              *(int4*)&xl[buf][m][c8] = st[it]; } }

    // ---- GEMM 1: K=2048 (zdm L1 or pr) ----
    f32x4 acc[2][4] = {};
    {
        const __hip_bfloat16* pB[4];
        #pragma unroll
        for (int nt = 0; nt < 4; ++nt)
            pB[nt] = w1 + (size_t)(nbase + nt * 16 + lr) * 2048 + lh * 8;

        LOADC(0); WRITEC(0); __syncthreads();
        for (int c = 0; c < 8; ++c) {
            if (c < 7) LOADC(c + 1);
            const __hip_bfloat16 (* const cur)[264] = xl[c & 1];
            bf16x8 bc[4];
            #pragma unroll
            for (int nt = 0; nt < 4; ++nt) bc[nt] = *(const bf16x8*)(pB[nt] + c * 256);
            #pragma unroll
            for (int k0 = 0; k0 < 256; k0 += 32) {
                bf16x8 bn[4];
                if (k0 + 32 < 256) {
                    #pragma unroll
                    for (int nt = 0; nt < 4; ++nt)
                        bn[nt] = *(const bf16x8*)(pB[nt] + c * 256 + k0 + 32);
                }
                const int kc = k0 + lh * 8;
                const bf16x8 a0f = *(const bf16x8*)&cur[lr][kc];
                const bf16x8 a1f = *(const bf16x8*)&cur[16 + lr][kc];
                #pragma unroll
                for (int nt = 0; nt < 4; ++nt) {
                    acc[0][nt] = MFMA16(a0f, bc[nt], acc[0][nt]);
                    acc[1][nt] = MFMA16(a1f, bc[nt], acc[1][nt]);
                }
                #pragma unroll
                for (int nt = 0; nt < 4; ++nt) bc[nt] = bn[nt];
            }
            if (c < 7) WRITEC((c + 1) & 1);
            __syncthreads();
        }
    }

    if (!is_zdm) {
        #pragma unroll
        for (int nt = 0; nt < 4; ++nt) {
            const int n = nbase + nt * 16 + lr;
            #pragma unroll
            for (int mt = 0; mt < 2; ++mt)
                #pragma unroll
                for (int v = 0; v < 4; ++v)
                    pr[(size_t)(a0 + mt * 16 + lh * 4 + v) * 256 + n] = acc[mt][nt][v];
        }
        return;
    }

    // ---- zdm L1 epilogue -> hl ----
    #pragma unroll
    for (int nt = 0; nt < 4; ++nt) {
        const int n = nbase + nt * 16 + lr;
        const float bv = zb1[n];
        #pragma unroll
        for (int mt = 0; mt < 2; ++mt)
            #pragma unroll
            for (int v = 0; v < 4; ++v) {
                float xv = acc[mt][nt][v] + bv;
                xv = xv >= 0.f ? xv : 0.01f * xv;
                hl[mt * 16 + lh * 4 + v][n] = __float2bfloat16(xv);
            }
    }
    __syncthreads();

    // ---- zdm L2: K=256, leaky, write back into hl ----
    {
        f32x4 acc2[2][4] = {};
        const __hip_bfloat16* pB[4];
        #pragma unroll
        for (int nt = 0; nt < 4; ++nt)
            pB[nt] = zT2 + (size_t)(nbase + nt * 16 + lr) * 256 + lh * 8;
        bf16x8 bc[4];
        #pragma unroll
        for (int nt = 0; nt < 4; ++nt) bc[nt] = *(const bf16x8*)(pB[nt]);
        #pragma unroll
        for (int k0 = 0; k0 < 256; k0 += 32) {
            bf16x8 bn[4];
            if (k0 + 32 < 256) {
                #pragma unroll
                for (int nt = 0; nt < 4; ++nt)
                    bn[nt] = *(const bf16x8*)(pB[nt] + k0 + 32);
            }
            const int kc = k0 + lh * 8;
            const bf16x8 a0f = *(const bf16x8*)&hl[lr][kc];
            const bf16x8 a1f = *(const bf16x8*)&hl[16 + lr][kc];
            #pragma unroll
            for (int nt = 0; nt < 4; ++nt) {
                acc2[0][nt] = MFMA16(a0f, bc[nt], acc2[0][nt]);
                acc2[1][nt] = MFMA16(a1f, bc[nt], acc2[1][nt]);
            }
            #pragma unroll
            for (int nt = 0; nt < 4; ++nt) bc[nt] = bn[nt];
        }
        __syncthreads();
        #pragma unroll
        for (int nt = 0; nt < 4; ++nt) {
            const int n = nbase + nt * 16 + lr;
            const float bv = zb2[n];
            #pragma unroll
            for (int mt = 0; mt < 2; ++mt)
                #pragma unroll
                for (int v = 0; v < 4; ++v) {
                    float xv = acc2[mt][nt][v] + bv;
                    xv = xv >= 0.f ? xv : 0.01f * xv;
                    hl[mt * 16 + lh * 4 + v][n] = __float2bfloat16(xv);
                }
        }
    }
    __syncthreads();

    // ---- zdm L3: K=256 -> qr (fp32, bias, no act) ----
    {
        f32x4 acc3[2][4] = {};
        const __hip_bfloat16* pB[4];
        #pragma unroll
        for (int nt = 0; nt < 4; ++nt)
            pB[nt] = zT3 + (size_t)(nbase + nt * 16 + lr) * 256 + lh * 8;
        bf16x8 bc[4];
        #pragma unroll
        for (int nt = 0; nt < 4; ++nt) bc[nt] = *(const bf16x8*)(pB[nt]);
        #pragma unroll
        for (int k0 = 0; k0 < 256; k0 += 32) {
            bf16x8 bn[4];
            if (k0 + 32 < 256) {
                #pragma unroll
                for (int nt = 0; nt < 4; ++nt)
                    bn[nt] = *(const bf16x8*)(pB[nt] + k0 + 32);
            }
            const int kc = k0 + lh * 8;
            const bf16x8 a0f = *(const bf16x8*)&hl[lr][kc];
            const bf16x8 a1f = *(const bf16x8*)&hl[16 + lr][kc];
            #pragma unroll
            for (int nt = 0; nt < 4; ++nt) {
                acc3[0][nt] = MFMA16(a0f, bc[nt], acc3[0][nt]);
                acc3[1][nt] = MFMA16(a1f, bc[nt], acc3[1][nt]);
            }
            #pragma unroll
            for (int nt = 0; nt < 4; ++nt) bc[nt] = bn[nt];
        }
        #pragma unroll
        for (int nt = 0; nt < 4; ++nt) {
            const int n = nbase + nt * 16 + lr;
            const float bv = zb3[n];
            #pragma unroll
            for (int mt = 0; mt < 2; ++mt)
                #pragma unroll
                for (int v = 0; v < 4; ++v)
                    qr[(size_t)(a0 + mt * 16 + lh * 4 + v) * 256 + n] = acc3[mt][nt][v] + bv;
        }
    }
    #undef LOADC
    #undef WRITEC
}

// ---------------------------------------------------------------------------
extern "C" void kernel_launch(void* const* d_in, const int* in_sizes, int n_in,
                              void* d_out, int out_size, void* d_ws, size_t ws_size,
                              hipStream_t stream)
{
    const float* q    = (const float*)d_in[0];
    const float* p    = (const float*)d_in[1];
    const float* amsk = (const float*)d_in[2];
    const float* sw1  = (const float*)d_in[3];
    const float* sb1  = (const float*)d_in[4];
    const float* sw2  = (const float*)d_in[5];
    const float* sb2  = (const float*)d_in[6];
    const float* sw3  = (const float*)d_in[7];
    const float* sb3  = (const float*)d_in[8];
    const float* zw1  = (const float*)d_in[9];
    const float* zb1  = (const float*)d_in[10];
    const float* zw2  = (const float*)d_in[11];
    const float* zb2  = (const float*)d_in[12];
    const float* zw3  = (const float*)d_in[13];
    const float* zb3  = (const float*)d_in[14];
    const float* zvw  = (const float*)d_in[15];

    // workspace carve-up
    char* ws = (char*)d_ws;
    size_t off = 0;
    __hip_bfloat16* qh   = (__hip_bfloat16*)(ws + off);  off += (size_t)R_TOT * 2048 * 2;
    __hip_bfloat16* ph   = (__hip_bfloat16*)(ws + off);  off += (size_t)R_TOT * 3 * 2048 * 2;
    __hip_bfloat16* wT1  = (__hip_bfloat16*)(ws + off);  off += 256 * 512 * 2;
    __hip_bfloat16* wT2  = (__hip_bfloat16*)(ws + off);  off += 256 * 256 * 2;
    __hip_bfloat16* wT3  = (__hip_bfloat16*)(ws + off);  off += 16 * 256 * 2;
    __hip_bfloat16* zT1  = (__hip_bfloat16*)(ws + off);  off += 256 * 2048 * 2;
    __hip_bfloat16* zT2  = (__hip_bfloat16*)(ws + off);  off += 256 * 256 * 2;
    __hip_bfloat16* zT3  = (__hip_bfloat16*)(ws + off);  off += 256 * 256 * 2;
    __hip_bfloat16* vT   = (__hip_bfloat16*)(ws + off);  off += 256 * 2048 * 2;

    float* qr = (float*)d_out;
    float* pr = (float*)d_out + QR_ELEMS;

    // 0) all weight transposes in one launch (1352 tiles)
    wtrans_all_kernel<<<1352, 256, 0, stream>>>(sw1, wT1, sw2, wT2, sw3, wT3,
                                                zw1, zT1, zw2, zT2, zw3, zT3, zvw, vT);
    // 1) fused sam MLP + softmax + pooling  (4 residues / block, 4 waves)
    sampool_kernel<<<R_TOT / 4, 256, 0, stream>>>(q, p, amsk, wT1, sb1, wT2, sb2, wT3, sb3, qh, ph);
    // 2) zdm (256 blocks) + pr (768 blocks) in one launch
    tail_kernel<<<1024, 256, 0, stream>>>(qh, ph, zT1, zb1, zT2, zb2, zT3, zb3, vT, qr, pr);

    (void)in_sizes; (void)n_in; (void)out_size; (void)ws_size;
}

// Round 13
// 422.567 us; speedup vs baseline: 1.3273x; 1.3273x over previous
//
#include <hip/hip_runtime.h>
#include <hip/hip_bf16.h>

// Problem constants
#define R_TOT   8192
#define A14     14
#define A_TOT   (R_TOT * A14)     // 114688
#define QR_ELEMS (R_TOT * 256)    // 2097152

typedef __attribute__((ext_vector_type(8))) short bf16x8;
typedef __attribute__((ext_vector_type(4))) float f32x4;
typedef __attribute__((ext_vector_type(4))) short short4v;

#define MFMA16(a, b, c) __builtin_amdgcn_mfma_f32_16x16x32_bf16((a), (b), (c), 0, 0, 0)

static __device__ __forceinline__ float b2f(short s) {
    return __uint_as_float(((unsigned)(unsigned short)s) << 16);
}

// ---------------------------------------------------------------------------
// Merged weight transpose + bf16 cast: all 7 weights in one launch.
// ---------------------------------------------------------------------------
static __device__ __forceinline__ void wtrans_tile(
    const float* __restrict__ w, __hip_bfloat16* __restrict__ wT,
    int K, int N, int kb, int nb, float* tile /*[32][33]*/)
{
    const int tx = threadIdx.x & 31, ty = threadIdx.x >> 5;   // 32 x 8
    #pragma unroll
    for (int i = 0; i < 32; i += 8) {
        int k = kb + ty + i, n = nb + tx;
        tile[(ty + i) * 33 + tx] = (k < K && n < N) ? w[(size_t)k * N + n] : 0.f;
    }
    __syncthreads();
    #pragma unroll
    for (int i = 0; i < 32; i += 8) {
        int n = nb + ty + i, k = kb + tx;
        if (n < N && k < K) wT[(size_t)n * K + k] = __float2bfloat16(tile[tx * 33 + ty + i]);
    }
}

__global__ __launch_bounds__(256) void wtrans_all_kernel(
    const float* __restrict__ sw1, __hip_bfloat16* __restrict__ wT1,
    const float* __restrict__ sw2, __hip_bfloat16* __restrict__ wT2,
    const float* __restrict__ sw3, __hip_bfloat16* __restrict__ wT3,
    const float* __restrict__ zw1, __hip_bfloat16* __restrict__ zT1,
    const float* __restrict__ zw2, __hip_bfloat16* __restrict__ zT2,
    const float* __restrict__ zw3, __hip_bfloat16* __restrict__ zT3,
    const float* __restrict__ zvw, __hip_bfloat16* __restrict__ vT)
{
    __shared__ float tile[32 * 33];
    int b = blockIdx.x;
    if (b < 128)      { wtrans_tile(sw1, wT1, 512, 256, (b % 16) * 32, (b / 16) * 32, tile); return; }
    b -= 128;
    if (b < 64)       { wtrans_tile(sw2, wT2, 256, 256, (b % 8) * 32, (b / 8) * 32, tile); return; }
    b -= 64;
    if (b < 8)        { wtrans_tile(sw3, wT3, 256, 16,  b * 32, 0, tile); return; }
    b -= 8;
    if (b < 512)      { wtrans_tile(zw1, zT1, 2048, 256, (b % 64) * 32, (b / 64) * 32, tile); return; }
    b -= 512;
    if (b < 64)       { wtrans_tile(zw2, zT2, 256, 256, (b % 8) * 32, (b / 8) * 32, tile); return; }
    b -= 64;
    if (b < 64)       { wtrans_tile(zw3, zT3, 256, 256, (b % 8) * 32, (b / 8) * 32, tile); return; }
    b -= 64;
    wtrans_tile(zvw, vT, 2048, 256, (b % 64) * 32, (b / 64) * 32, tile);
}

// ---------------------------------------------------------------------------
// Fused sam MLP + masked softmax + pooling, v10: small-accumulator / high-
// occupancy configuration.
// Block = 4 residues (M=64), 512 threads = 8 waves; waves split N 8 ways
// (32 cols each) -> acc[4][2] = 32 AGPR.  Unified-RF occupancy model
// (fitted r2-r12): waves/SIMD = floor(512 / round16(VGPR+AGPR)).
// Target: ~80 arch + 32 acc = 112 -> 4 waves/SIMD = 16 waves/CU (2 blocks).
// B-prefetch depth 2 + A depth 1 (r12 showed depth 1 costs ~30%).
// z[64][520]: q-half (cols 0-255) stays live for pooling; norm half
// (cols 256-511) overwritten by h1 then h2.  LDS 74,240 B; 2 blocks fit.
// ---------------------------------------------------------------------------
__global__ __launch_bounds__(512, 4) void sampool_kernel(
    const float* __restrict__ q, const float* __restrict__ p,
    const float* __restrict__ atom_mask,
    const __hip_bfloat16* __restrict__ wT1, const float* __restrict__ b1,
    const __hip_bfloat16* __restrict__ wT2, const float* __restrict__ b2,
    const __hip_bfloat16* __restrict__ wT3, const float* __restrict__ b3,
    __hip_bfloat16* __restrict__ qh, __hip_bfloat16* __restrict__ ph)
{
    __shared__ __align__(16) __hip_bfloat16 zl[64][520];    // 66,560 B
    __shared__ float sa_lds[64][16];                        //  4,096 B
    __shared__ float aw_lds[2][4][14][8];                   //  3,584 B

    const int tid = threadIdx.x;
    const int r0  = blockIdx.x * 4;      // 4 residues
    const int a0  = r0 * A14;            // 56 real atom rows, pad to 64
    const int wv  = tid >> 6;            // 0..7
    const int l   = tid & 63;
    const int lr  = l & 15;
    const int lh  = l >> 4;
    const int nbase = wv * 32;           // 32-col slice per wave

    // ---- stage q-half (cols 0-255): 4096 float4 jobs / 512 thr = 8 each.
    //      Burst: all 8 loads in flight before converts (acc not yet live).
    {
        float4 qv[8];
        #pragma unroll
        for (int it = 0; it < 8; ++it) {
            const int g  = tid + it * 512;
            const int m  = g >> 6;
            const int c4 = (g & 63) * 4;
            const int ar = a0 + m;
            const size_t arow = (size_t)((ar < A_TOT) ? ar : (A_TOT - 1));
            qv[it] = *(const float4*)&q[arow * 256 + c4];
        }
        #pragma unroll
        for (int it = 0; it < 8; ++it) {
            const int g  = tid + it * 512;
            const int m  = g >> 6;
            const int c4 = (g & 63) * 4;
            __hip_bfloat16 t[4];
            t[0] = __float2bfloat16(qv[it].x); t[1] = __float2bfloat16(qv[it].y);
            t[2] = __float2bfloat16(qv[it].z); t[3] = __float2bfloat16(qv[it].w);
            *(short4v*)&zl[m][c4] = *(const short4v*)t;
        }
    }
    // ---- stage norm-half (cols 256-511): 8 jobs, chunks of 4 (12 loads) ----
    #pragma unroll
    for (int ch = 0; ch < 2; ++ch) {
        float4 na[4], nb[4], nc[4];
        #pragma unroll
        for (int i = 0; i < 4; ++i) {
            const int g  = tid + (ch * 4 + i) * 512;
            const int m  = g >> 6;
            const int cc = (g & 63) * 4;
            const int ar = a0 + m;
            const size_t arow = (size_t)((ar < A_TOT) ? ar : (A_TOT - 1));
            const float* base = p + arow * 768 + cc;
            na[i] = *(const float4*)(base);
            nb[i] = *(const float4*)(base + 256);
            nc[i] = *(const float4*)(base + 512);
        }
        #pragma unroll
        for (int i = 0; i < 4; ++i) {
            const int g  = tid + (ch * 4 + i) * 512;
            const int m  = g >> 6;
            const int cc = (g & 63) * 4;
            __hip_bfloat16 t[4];
            t[0] = __float2bfloat16(sqrtf(na[i].x*na[i].x + nb[i].x*nb[i].x + nc[i].x*nc[i].x + 1e-6f));
            t[1] = __float2bfloat16(sqrtf(na[i].y*na[i].y + nb[i].y*nb[i].y + nc[i].y*nc[i].y + 1e-6f));
            t[2] = __float2bfloat16(sqrtf(na[i].z*na[i].z + nb[i].z*nb[i].z + nc[i].z*nc[i].z + 1e-6f));
            t[3] = __float2bfloat16(sqrtf(na[i].w*na[i].w + nb[i].w*nb[i].w + nc[i].w*nc[i].w + 1e-6f));
            *(short4v*)&zl[m][256 + cc] = *(const short4v*)t;
        }
    }
    __syncthreads();   // (A) z fully staged

    // ---- Layer 1: K=512 -> N=256 (32/wave); 8 MFMA/k-step, B depth-2 ----
    f32x4 acc[4][2] = {};
    {
        const __hip_bfloat16* pB[2];
        #pragma unroll
        for (int nt = 0; nt < 2; ++nt)
            pB[nt] = wT1 + (size_t)(nbase + nt * 16 + lr) * 512 + lh * 8;
        bf16x8 bc[2], b1v[2];
        #pragma unroll
        for (int nt = 0; nt < 2; ++nt) { bc[nt]  = *(const bf16x8*)(pB[nt]);
                                         b1v[nt] = *(const bf16x8*)(pB[nt] + 32); }
        bf16x8 ac[4];
        #pragma unroll
        for (int mf = 0; mf < 4; ++mf)
            ac[mf] = *(const bf16x8*)&zl[mf * 16 + lr][lh * 8];

        #pragma unroll
        for (int k0 = 0; k0 < 512; k0 += 32) {
            bf16x8 b2v[2], an[4];
            if (k0 + 64 < 512) {
                #pragma unroll
                for (int nt = 0; nt < 2; ++nt)
                    b2v[nt] = *(const bf16x8*)(pB[nt] + k0 + 64);
            }
            if (k0 + 32 < 512) {
                #pragma unroll
                for (int mf = 0; mf < 4; ++mf)
                    an[mf] = *(const bf16x8*)&zl[mf * 16 + lr][k0 + 32 + lh * 8];
            }
            #pragma unroll
            for (int mf = 0; mf < 4; ++mf)
                #pragma unroll
                for (int nt = 0; nt < 2; ++nt)
                    acc[mf][nt] = MFMA16(ac[mf], bc[nt], acc[mf][nt]);
            #pragma unroll
            for (int nt = 0; nt < 2; ++nt) { bc[nt] = b1v[nt]; b1v[nt] = b2v[nt]; }
            #pragma unroll
            for (int mf = 0; mf < 4; ++mf) ac[mf] = an[mf];
        }
        __syncthreads();   // (B) all waves done reading z norm half
        #pragma unroll
        for (int nt = 0; nt < 2; ++nt) {
            const int n = nbase + nt * 16 + lr;
            const float bv = b1[n];
            #pragma unroll
            for (int mf = 0; mf < 4; ++mf)
                #pragma unroll
                for (int v = 0; v < 4; ++v) {
                    float x = acc[mf][nt][v] + bv;
                    x = x >= 0.f ? x : 0.01f * x;
                    zl[mf * 16 + lh * 4 + v][256 + n] = __float2bfloat16(x);  // h1
                }
        }
    }
    __syncthreads();   // (C) h1 complete

    // ---- Layer 2: K=256, leaky; A=h1 (z cols 256+), in-place h2 ----
    {
        f32x4 acc2[4][2] = {};
        const __hip_bfloat16* pB2[2];
        #pragma unroll
        for (int nt = 0; nt < 2; ++nt)
            pB2[nt] = wT2 + (size_t)(nbase + nt * 16 + lr) * 256 + lh * 8;
        bf16x8 bc[2], b1v[2];
        #pragma unroll
        for (int nt = 0; nt < 2; ++nt) { bc[nt]  = *(const bf16x8*)(pB2[nt]);
                                         b1v[nt] = *(const bf16x8*)(pB2[nt] + 32); }
        bf16x8 ac[4];
        #pragma unroll
        for (int mf = 0; mf < 4; ++mf)
            ac[mf] = *(const bf16x8*)&zl[mf * 16 + lr][256 + lh * 8];

        #pragma unroll
        for (int k0 = 0; k0 < 256; k0 += 32) {
            bf16x8 b2v[2], an[4];
            if (k0 + 64 < 256) {
                #pragma unroll
                for (int nt = 0; nt < 2; ++nt)
                    b2v[nt] = *(const bf16x8*)(pB2[nt] + k0 + 64);
            }
            if (k0 + 32 < 256) {
                #pragma unroll
                for (int mf = 0; mf < 4; ++mf)
                    an[mf] = *(const bf16x8*)&zl[mf * 16 + lr][256 + k0 + 32 + lh * 8];
            }
            #pragma unroll
            for (int mf = 0; mf < 4; ++mf)
                #pragma unroll
                for (int nt = 0; nt < 2; ++nt)
                    acc2[mf][nt] = MFMA16(ac[mf], bc[nt], acc2[mf][nt]);
            #pragma unroll
            for (int nt = 0; nt < 2; ++nt) { bc[nt] = b1v[nt]; b1v[nt] = b2v[nt]; }
            #pragma unroll
            for (int mf = 0; mf < 4; ++mf) ac[mf] = an[mf];
        }
        __syncthreads();   // (D) all reads of h1 done
        #pragma unroll
        for (int nt = 0; nt < 2; ++nt) {
            const int n = nbase + nt * 16 + lr;
            const float bv = b2[n];
            #pragma unroll
            for (int mf = 0; mf < 4; ++mf)
                #pragma unroll
                for (int v = 0; v < 4; ++v) {
                    float x = acc2[mf][nt][v] + bv;
                    x = x >= 0.f ? x : 0.01f * x;
                    zl[mf * 16 + lh * 4 + v][256 + n] = __float2bfloat16(x);  // h2
                }
        }
    }
    __syncthreads();   // (E) h2 complete

    // ---- Layer 3: K=256 -> 16 cols; waves 0..3 own m-frags 0..3 ----
    if (wv < 4) {
        f32x4 a3 = {};
        const __hip_bfloat16* pW3 = wT3 + (size_t)lr * 256 + lh * 8;
        bf16x8 bwc = *(const bf16x8*)(pW3);
        bf16x8 bw1 = *(const bf16x8*)(pW3 + 32);
        #pragma unroll
        for (int k0 = 0; k0 < 256; k0 += 32) {
            bf16x8 bw2;
            if (k0 + 64 < 256) bw2 = *(const bf16x8*)(pW3 + k0 + 64);
            const bf16x8 af = *(const bf16x8*)&zl[wv * 16 + lr][256 + k0 + lh * 8];
            a3 = MFMA16(af, bwc, a3);
            bwc = bw1; bw1 = bw2;
        }
        const float bv = b3[lr];
        #pragma unroll
        for (int v = 0; v < 4; ++v)
            sa_lds[wv * 16 + lh * 4 + v][lr] = a3[v] + bv;
    }
    __syncthreads();   // (F) sa complete

    // ---- masked softmax: 4 residues x 16 channels = 64 threads ----
    if (tid < 64) {
        const int res = tid >> 4, ch = tid & 15;
        const size_t rg = (size_t)(r0 + res);
        float sl[14];
        float mx = -3.0e38f, anym = 0.f;
        #pragma unroll
        for (int a = 0; a < 14; ++a) {
            const float m = atom_mask[rg * 14 + a];
            anym = fmaxf(anym, m);
            const float lm = (1.0f - m + 1e-6f) / (m - 1e-6f);
            const float v = sa_lds[res * 14 + a][ch] + lm;
            sl[a] = v;
            mx = fmaxf(mx, v);
        }
        float s = 0.f;
        #pragma unroll
        for (int a = 0; a < 14; ++a) { sl[a] = expf(sl[a] - mx); s += sl[a]; }
        const float inv = ((anym != 0.f) ? 1.f : 0.f) / s;   // fold residue mask
        const int h = ch >> 1;
        #pragma unroll
        for (int a = 0; a < 14; ++a)
            aw_lds[ch & 1][res][a][h] = sl[a] * inv;
    }
    __syncthreads();   // (G) aw complete

    // ---- pooling: 1024 jobs = 4 res x {q,px0,px1,px2} x 64 c-quads;
    //      512 threads -> 2 jobs each.  q read from LDS z (cols 0-255). ----
    #pragma unroll
    for (int jr = 0; jr < 2; ++jr) {
        const int job = tid + jr * 512;
        const int res = job >> 8;            // 0..3
        const int s   = (job >> 6) & 3;      // 0:q  1..3:p[x]
        const int c4  = (job & 63) * 4;
        const size_t rg = (size_t)(r0 + res);
        const float* const aw = &aw_lds[(s == 0) ? 0 : 1][res][0][0];
        float acc4[4][8] = {};
        if (s == 0) {
            #pragma unroll
            for (int a = 0; a < 14; ++a) {
                const short4v qv = *(const short4v*)&zl[res * 14 + a][c4];
                const float qf[4] = { b2f(qv.x), b2f(qv.y), b2f(qv.z), b2f(qv.w) };
                #pragma unroll
                for (int ci = 0; ci < 4; ++ci)
                    #pragma unroll
                    for (int h = 0; h < 8; ++h)
                        acc4[ci][h] = fmaf(qf[ci], aw[a * 8 + h], acc4[ci][h]);
            }
        } else {
            const int x = s - 1;
            #pragma unroll
            for (int a = 0; a < 14; ++a) {
                const float4 pv = *(const float4*)&p[(rg * 14 + a) * 768 + (size_t)x * 256 + c4];
                const float pf[4] = { pv.x, pv.y, pv.z, pv.w };
                #pragma unroll
                for (int ci = 0; ci < 4; ++ci)
                    #pragma unroll
                    for (int h = 0; h < 8; ++h)
                        acc4[ci][h] = fmaf(pf[ci], aw[a * 8 + h], acc4[ci][h]);
            }
        }
        alignas(16) __hip_bfloat16 tmp[32];
        #pragma unroll
        for (int ci = 0; ci < 4; ++ci)
            #pragma unroll
            for (int h = 0; h < 8; ++h)
                tmp[ci * 8 + h] = __float2bfloat16(acc4[ci][h]);
        __hip_bfloat16* const dst = (s == 0)
            ? &qh[rg * 2048 + (size_t)c4 * 8]
            : &ph[(rg * 3 + (s - 1)) * 2048 + (size_t)c4 * 8];
        #pragma unroll
        for (int u = 0; u < 4; ++u)
            *reinterpret_cast<int4*>(dst + u * 8) = *reinterpret_cast<const int4*>(tmp + u * 8);
    }
}

// ---------------------------------------------------------------------------
// Merged tail: blocks 0..255 run zdm (qh -> qr), blocks 256..1023 run pr
// (ph @ vT -> pr).
// ---------------------------------------------------------------------------
__global__ __launch_bounds__(256, 3) void tail_kernel(
    const __hip_bfloat16* __restrict__ qh, const __hip_bfloat16* __restrict__ ph,
    const __hip_bfloat16* __restrict__ zT1, const float* __restrict__ zb1,
    const __hip_bfloat16* __restrict__ zT2, const float* __restrict__ zb2,
    const __hip_bfloat16* __restrict__ zT3, const float* __restrict__ zb3,
    const __hip_bfloat16* __restrict__ vT,
    float* __restrict__ qr, float* __restrict__ pr)
{
    __shared__ __align__(16) __hip_bfloat16 xl[2][32][264];  // 33,792 B
    __shared__ __align__(16) __hip_bfloat16 hl[32][264];     // 16,896 B

    const int tid = threadIdx.x;
    const int wv  = tid >> 6;
    const int l   = tid & 63;
    const int lr  = l & 15;
    const int lh  = l >> 4;
    const int nbase = wv * 64;
    const bool is_zdm = (blockIdx.x < 256);
    const int a0 = (is_zdm ? blockIdx.x : (blockIdx.x - 256)) * 32;
    const __hip_bfloat16* const x = is_zdm ? qh : ph;
    const __hip_bfloat16* const w1 = is_zdm ? zT1 : vT;

    int4 st[4];
    #define LOADC(c)                                                          \
        { _Pragma("unroll")                                                   \
          for (int it = 0; it < 4; ++it) {                                    \
              const int g = tid + it * 256;                                   \
              const int m = g >> 5, c8 = (g & 31) * 8;                        \
              st[it] = *(const int4*)&x[(size_t)(a0 + m) * 2048 + (c) * 256 + c8]; } }
    #define WRITEC(buf)                                                       \
        { _Pragma("unroll")                                                   \
          for (int it = 0; it < 4; ++it) {                                    \
              const int g = tid + it * 256;                                   \
              const int m = g >> 5, c8 = (g & 31) * 8;                        \
              *(int4*)&xl[buf][m][c8] = st[it]; } }

    // ---- GEMM 1: K=2048 (zdm L1 or pr) ----
    f32x4 acc[2][4] = {};
    {
        const __hip_bfloat16* pB[4];
        #pragma unroll
        for (int nt = 0; nt < 4; ++nt)
            pB[nt] = w1 + (size_t)(nbase + nt * 16 + lr) * 2048 + lh * 8;

        LOADC(0); WRITEC(0); __syncthreads();
        for (int c = 0; c < 8; ++c) {
            if (c < 7) LOADC(c + 1);
            const __hip_bfloat16 (* const cur)[264] = xl[c & 1];
            bf16x8 bc[4];
            #pragma unroll
            for (int nt = 0; nt < 4; ++nt) bc[nt] = *(const bf16x8*)(pB[nt] + c * 256);
            #pragma unroll
            for (int k0 = 0; k0 < 256; k0 += 32) {
                bf16x8 bn[4];
                if (k0 + 32 < 256) {
                    #pragma unroll
                    for (int nt = 0; nt < 4; ++nt)
                        bn[nt] = *(const bf16x8*)(pB[nt] + c * 256 + k0 + 32);
                }
                const int kc = k0 + lh * 8;
                const bf16x8 a0f = *(const bf16x8*)&cur[lr][kc];
                const bf16x8 a1f = *(const bf16x8*)&cur[16 + lr][kc];
                #pragma unroll
                for (int nt = 0; nt < 4; ++nt) {
                    acc[0][nt] = MFMA16(a0f, bc[nt], acc[0][nt]);
                    acc[1][nt] = MFMA16(a1f, bc[nt], acc[1][nt]);
                }
                #pragma unroll
                for (int nt = 0; nt < 4; ++nt) bc[nt] = bn[nt];
            }
            if (c < 7) WRITEC((c + 1) & 1);
            __syncthreads();
        }
    }

    if (!is_zdm) {
        #pragma unroll
        for (int nt = 0; nt < 4; ++nt) {
            const int n = nbase + nt * 16 + lr;
            #pragma unroll
            for (int mt = 0; mt < 2; ++mt)
                #pragma unroll
                for (int v = 0; v < 4; ++v)
                    pr[(size_t)(a0 + mt * 16 + lh * 4 + v) * 256 + n] = acc[mt][nt][v];
        }
        return;
    }

    // ---- zdm L1 epilogue -> hl ----
    #pragma unroll
    for (int nt = 0; nt < 4; ++nt) {
        const int n = nbase + nt * 16 + lr;
        const float bv = zb1[n];
        #pragma unroll
        for (int mt = 0; mt < 2; ++mt)
            #pragma unroll
            for (int v = 0; v < 4; ++v) {
                float xv = acc[mt][nt][v] + bv;
                xv = xv >= 0.f ? xv : 0.01f * xv;
                hl[mt * 16 + lh * 4 + v][n] = __float2bfloat16(xv);
            }
    }
    __syncthreads();

    // ---- zdm L2: K=256, leaky, write back into hl ----
    {
        f32x4 acc2[2][4] = {};
        const __hip_bfloat16* pB[4];
        #pragma unroll
        for (int nt = 0; nt < 4; ++nt)
            pB[nt] = zT2 + (size_t)(nbase + nt * 16 + lr) * 256 + lh * 8;
        bf16x8 bc[4];
        #pragma unroll
        for (int nt = 0; nt < 4; ++nt) bc[nt] = *(const bf16x8*)(pB[nt]);
        #pragma unroll
        for (int k0 = 0; k0 < 256; k0 += 32) {
            bf16x8 bn[4];
            if (k0 + 32 < 256) {
                #pragma unroll
                for (int nt = 0; nt < 4; ++nt)
                    bn[nt] = *(const bf16x8*)(pB[nt] + k0 + 32);
            }
            const int kc = k0 + lh * 8;
            const bf16x8 a0f = *(const bf16x8*)&hl[lr][kc];
            const bf16x8 a1f = *(const bf16x8*)&hl[16 + lr][kc];
            #pragma unroll
            for (int nt = 0; nt < 4; ++nt) {
                acc2[0][nt] = MFMA16(a0f, bc[nt], acc2[0][nt]);
                acc2[1][nt] = MFMA16(a1f, bc[nt], acc2[1][nt]);
            }
            #pragma unroll
            for (int nt = 0; nt < 4; ++nt) bc[nt] = bn[nt];
        }
        __syncthreads();
        #pragma unroll
        for (int nt = 0; nt < 4; ++nt) {
            const int n = nbase + nt * 16 + lr;
            const float bv = zb2[n];
            #pragma unroll
            for (int mt = 0; mt < 2; ++mt)
                #pragma unroll
                for (int v = 0; v < 4; ++v) {
                    float xv = acc2[mt][nt][v] + bv;
                    xv = xv >= 0.f ? xv : 0.01f * xv;
                    hl[mt * 16 + lh * 4 + v][n] = __float2bfloat16(xv);
                }
        }
    }
    __syncthreads();

    // ---- zdm L3: K=256 -> qr (fp32, bias, no act) ----
    {
        f32x4 acc3[2][4] = {};
        const __hip_bfloat16* pB[4];
        #pragma unroll
        for (int nt = 0; nt < 4; ++nt)
            pB[nt] = zT3 + (size_t)(nbase + nt * 16 + lr) * 256 + lh * 8;
        bf16x8 bc[4];
        #pragma unroll
        for (int nt = 0; nt < 4; ++nt) bc[nt] = *(const bf16x8*)(pB[nt]);
        #pragma unroll
        for (int k0 = 0; k0 < 256; k0 += 32) {
            bf16x8 bn[4];
            if (k0 + 32 < 256) {
                #pragma unroll
                for (int nt = 0; nt < 4; ++nt)
                    bn[nt] = *(const bf16x8*)(pB[nt] + k0 + 32);
            }
            const int kc = k0 + lh * 8;
            const bf16x8 a0f = *(const bf16x8*)&hl[lr][kc];
            const bf16x8 a1f = *(const bf16x8*)&hl[16 + lr][kc];
            #pragma unroll
            for (int nt = 0; nt < 4; ++nt) {
                acc3[0][nt] = MFMA16(a0f, bc[nt], acc3[0][nt]);
                acc3[1][nt] = MFMA16(a1f, bc[nt], acc3[1][nt]);
            }
            #pragma unroll
            for (int nt = 0; nt < 4; ++nt) bc[nt] = bn[nt];
        }
        #pragma unroll
        for (int nt = 0; nt < 4; ++nt) {
            const int n = nbase + nt * 16 + lr;
            const float bv = zb3[n];
            #pragma unroll
            for (int mt = 0; mt < 2; ++mt)
                #pragma unroll
                for (int v = 0; v < 4; ++v)
                    qr[(size_t)(a0 + mt * 16 + lh * 4 + v) * 256 + n] = acc3[mt][nt][v] + bv;
        }
    }
    #undef LOADC
    #undef WRITEC
}

// ---------------------------------------------------------------------------
extern "C" void kernel_launch(void* const* d_in, const int* in_sizes, int n_in,
                              void* d_out, int out_size, void* d_ws, size_t ws_size,
                              hipStream_t stream)
{
    const float* q    = (const float*)d_in[0];
    const float* p    = (const float*)d_in[1];
    const float* amsk = (const float*)d_in[2];
    const float* sw1  = (const float*)d_in[3];
    const float* sb1  = (const float*)d_in[4];
    const float* sw2  = (const float*)d_in[5];
    const float* sb2  = (const float*)d_in[6];
    const float* sw3  = (const float*)d_in[7];
    const float* sb3  = (const float*)d_in[8];
    const float* zw1  = (const float*)d_in[9];
    const float* zb1  = (const float*)d_in[10];
    const float* zw2  = (const float*)d_in[11];
    const float* zb2  = (const float*)d_in[12];
    const float* zw3  = (const float*)d_in[13];
    const float* zb3  = (const float*)d_in[14];
    const float* zvw  = (const float*)d_in[15];

    // workspace carve-up
    char* ws = (char*)d_ws;
    size_t off = 0;
    __hip_bfloat16* qh   = (__hip_bfloat16*)(ws + off);  off += (size_t)R_TOT * 2048 * 2;
    __hip_bfloat16* ph   = (__hip_bfloat16*)(ws + off);  off += (size_t)R_TOT * 3 * 2048 * 2;
    __hip_bfloat16* wT1  = (__hip_bfloat16*)(ws + off);  off += 256 * 512 * 2;
    __hip_bfloat16* wT2  = (__hip_bfloat16*)(ws + off);  off += 256 * 256 * 2;
    __hip_bfloat16* wT3  = (__hip_bfloat16*)(ws + off);  off += 16 * 256 * 2;
    __hip_bfloat16* zT1  = (__hip_bfloat16*)(ws + off);  off += 256 * 2048 * 2;
    __hip_bfloat16* zT2  = (__hip_bfloat16*)(ws + off);  off += 256 * 256 * 2;
    __hip_bfloat16* zT3  = (__hip_bfloat16*)(ws + off);  off += 256 * 256 * 2;
    __hip_bfloat16* vT   = (__hip_bfloat16*)(ws + off);  off += 256 * 2048 * 2;

    float* qr = (float*)d_out;
    float* pr = (float*)d_out + QR_ELEMS;

    // 0) all weight transposes in one launch (1352 tiles)
    wtrans_all_kernel<<<1352, 256, 0, stream>>>(sw1, wT1, sw2, wT2, sw3, wT3,
                                                zw1, zT1, zw2, zT2, zw3, zT3, zvw, vT);
    // 1) fused sam MLP + softmax + pooling  (4 residues / block, 8 waves)
    sampool_kernel<<<R_TOT / 4, 512, 0, stream>>>(q, p, amsk, wT1, sb1, wT2, sb2, wT3, sb3, qh, ph);
    // 2) zdm (256 blocks) + pr (768 blocks) in one launch
    tail_kernel<<<1024, 256, 0, stream>>>(qh, ph, zT1, zb1, zT2, zb2, zT3, zb3, vT, qr, pr);

    (void)in_sizes; (void)n_in; (void)out_size; (void)ws_size;
}